// Round 1
// baseline (6343.563 us; speedup 1.0000x reference)
//
#include <hip/hip_runtime.h>

#define NN 100000
#define NE 1600000
#define FIN 128
#define HID 64
#define HEADS 8
#define KORD 14
#define NGRAPHS 128
#define NCLASSES 10

static inline size_t align256(size_t x) { return (x + 255) & ~(size_t)255; }

// ---------------- setup kernels ----------------

__global__ void k_deg(const int* __restrict__ row, int* __restrict__ deg, int ne) {
    int e = blockIdx.x * 256 + threadIdx.x;
    if (e < ne) atomicAdd(&deg[row[e]], 1);
}

__global__ void k_dinv(const int* __restrict__ deg, float* __restrict__ dinv, int n) {
    int i = blockIdx.x * 256 + threadIdx.x;
    if (i < n) {
        float d = (float)deg[i];
        dinv[i] = rsqrtf(d < 1.f ? 1.f : d);
    }
}

// exclusive scan phase 1: per-block scan of 256 elements
__global__ void k_scan1(const int* __restrict__ deg, int* __restrict__ rowptr,
                        int* __restrict__ bsum, int n) {
    __shared__ int s[256];
    int t = threadIdx.x;
    int i = blockIdx.x * 256 + t;
    int v = (i < n) ? deg[i] : 0;
    s[t] = v;
    __syncthreads();
    for (int off = 1; off < 256; off <<= 1) {
        int add = (t >= off) ? s[t - off] : 0;
        __syncthreads();
        s[t] += add;
        __syncthreads();
    }
    if (i < n) rowptr[i] = s[t] - v;  // exclusive within block
    if (t == 255) bsum[blockIdx.x] = s[255];
}

// phase 2: single-block exclusive scan of block sums (nb <= 1024)
__global__ void k_scan2(int* __restrict__ bsum, int nb) {
    __shared__ int s[1024];
    int t = threadIdx.x;
    int v = (t < nb) ? bsum[t] : 0;
    s[t] = v;
    __syncthreads();
    for (int off = 1; off < 1024; off <<= 1) {
        int add = (t >= off) ? s[t - off] : 0;
        __syncthreads();
        s[t] += add;
        __syncthreads();
    }
    if (t < nb) bsum[t] = s[t] - v;  // exclusive
}

// phase 3: add block offsets; init cursor; write rowptr[n]
__global__ void k_scan3(int* __restrict__ rowptr, int* __restrict__ cursor,
                        const int* __restrict__ bsum, int n, int etot) {
    int i = blockIdx.x * 256 + threadIdx.x;
    if (i == 0) rowptr[n] = etot;
    if (i < n) {
        int v = rowptr[i] + bsum[i >> 8];
        rowptr[i] = v;
        cursor[i] = v;
    }
}

__global__ void k_fill(const int* __restrict__ row, const int* __restrict__ col,
                       const float* __restrict__ dinv, int* __restrict__ cursor,
                       int* __restrict__ ccol, float* __restrict__ cnorm, int ne) {
    int e = blockIdx.x * 256 + threadIdx.x;
    if (e >= ne) return;
    int r = row[e], c = col[e];
    int pos = atomicAdd(&cursor[r], 1);
    ccol[pos] = c;
    cnorm[pos] = dinv[r] * dinv[c];
}

// coeff[l][k] = mean over heads of theta[l][h][k]
__global__ void k_coeff(const float* __restrict__ th1, const float* __restrict__ ths,
                        float* __restrict__ coeff) {
    int i = threadIdx.x;
    if (i >= 3 * KORD) return;
    int l = i / KORD, k = i % KORD;
    const float* t = (l == 0) ? th1 : ths + (l - 1) * HEADS * KORD;
    float s = 0.f;
    for (int h = 0; h < HEADS; ++h) s += t[h * KORD + k];
    coeff[i] = s * (1.f / HEADS);
}

// ---------------- main compute kernels ----------------

// y[n x 64] = h[n x F] @ W[F x 64]; W staged in LDS; 4 rows/block, thread per output
template <int F>
__global__ void k_gemm(const float* __restrict__ h, const float* __restrict__ W,
                       float* __restrict__ y, int n) {
    __shared__ float Wl[F * 64];
    int tid = threadIdx.x;
    for (int i = tid; i < F * 64; i += 256) Wl[i] = W[i];
    __syncthreads();
    int row = blockIdx.x * 4 + (tid >> 6);
    int col = tid & 63;
    if (row >= n) return;
    const float* hr = h + (size_t)row * F;
    float acc = 0.f;
#pragma unroll 8
    for (int f = 0; f < F; ++f) acc += hr[f] * Wl[f * 64 + col];
    y[(size_t)row * 64 + col] = acc;
}

// One wave per row, lane = feature. p = -sum_{e in row} norm*src[col].
// MODE 0: first step  : write tcur (prevbuf) = p ; out = c0*yA + c1*p
// MODE 1: middle step : tn = 2p - prev ; prev = tn ; out += c_k*tn
// MODE 2: last step   : tn = 2p - prev ; out = relu(out + c_k*tn + bias)
template <int MODE>
__global__ void k_prop(const int* __restrict__ rowptr, const int* __restrict__ ccol,
                       const float* __restrict__ cnorm, const float* __restrict__ src,
                       float* __restrict__ prevbuf, const float* yA,
                       float* __restrict__ outbuf, const float* __restrict__ coeff,
                       int k, const float* __restrict__ bias, int n) {
    int wid = (blockIdx.x * blockDim.x + threadIdx.x) >> 6;
    int lane = threadIdx.x & 63;
    if (wid >= n) return;
    int e0 = rowptr[wid], e1 = rowptr[wid + 1];
    float acc = 0.f;
    for (int e = e0; e < e1; ++e) {
        int c = ccol[e];
        float w = cnorm[e];
        acc += w * src[c * 64 + lane];
    }
    float p = -acc;
    int idx = wid * 64 + lane;
    if (MODE == 0) {
        prevbuf[idx] = p;
        outbuf[idx] = coeff[0] * yA[idx] + coeff[1] * p;
    } else {
        float tn = 2.f * p - prevbuf[idx];
        if (MODE == 1) {
            prevbuf[idx] = tn;
            outbuf[idx] += coeff[k] * tn;
        } else {
            float v = outbuf[idx] + coeff[k] * tn + bias[lane];
            outbuf[idx] = v > 0.f ? v : 0.f;
        }
    }
}

// run-length compressed segment sum over sorted batch; wave = 32 nodes, lane = feature
__global__ void k_pool(const float* __restrict__ h, const int* __restrict__ batch,
                       float* __restrict__ sums, float* __restrict__ cntf, int n) {
    int wid = (blockIdx.x * blockDim.x + threadIdx.x) >> 6;
    int lane = threadIdx.x & 63;
    int start = wid * 32;
    if (start >= n) return;
    int end = start + 32;
    if (end > n) end = n;
    float acc = 0.f;
    int run = 0;
    int g = batch[start];
    for (int i = start; i < end; ++i) {
        int gi = batch[i];
        if (gi != g) {
            atomicAdd(&sums[g * 64 + lane], acc);
            if (lane == 0) atomicAdd(&cntf[g], (float)run);
            acc = 0.f;
            run = 0;
            g = gi;
        }
        acc += h[(size_t)i * 64 + lane];
        run++;
    }
    atomicAdd(&sums[g * 64 + lane], acc);
    if (lane == 0) atomicAdd(&cntf[g], (float)run);
}

// per-graph head: pooled = sums/cnt ; g = relu(pooled@w1+b1) ; logits = g@w2+b2 ; log_softmax
__global__ void k_head(const float* __restrict__ sums, const float* __restrict__ cntf,
                       const float* __restrict__ w1, const float* __restrict__ b1,
                       const float* __restrict__ w2, const float* __restrict__ b2,
                       float* __restrict__ out) {
    __shared__ float pl[64], gl[64], lg[NCLASSES];
    int g = blockIdx.x, t = threadIdx.x;
    float c = cntf[g];
    if (c < 1.f) c = 1.f;
    pl[t] = sums[g * 64 + t] / c;
    __syncthreads();
    float a = b1[t];
    for (int f = 0; f < 64; ++f) a += pl[f] * w1[f * 64 + t];
    gl[t] = a > 0.f ? a : 0.f;
    __syncthreads();
    if (t < NCLASSES) {
        float a2 = b2[t];
        for (int f = 0; f < 64; ++f) a2 += gl[f] * w2[f * NCLASSES + t];
        lg[t] = a2;
    }
    __syncthreads();
    if (t < NCLASSES) {
        float m = lg[0];
        for (int i = 1; i < NCLASSES; ++i) m = fmaxf(m, lg[i]);
        float s = 0.f;
        for (int i = 0; i < NCLASSES; ++i) s += expf(lg[i] - m);
        out[g * NCLASSES + t] = lg[t] - m - logf(s);
    }
}

// ---------------- host ----------------

extern "C" void kernel_launch(void* const* d_in, const int* in_sizes, int n_in,
                              void* d_out, int out_size, void* d_ws, size_t ws_size,
                              hipStream_t stream) {
    const float* x   = (const float*)d_in[0];
    const int*   ei  = (const int*)d_in[1];
    const int*   bat = (const int*)d_in[2];
    const float* W1  = (const float*)d_in[3];
    const float* th1 = (const float*)d_in[4];
    const float* b1  = (const float*)d_in[5];
    const float* Ws  = (const float*)d_in[6];
    const float* ths = (const float*)d_in[7];
    const float* bs  = (const float*)d_in[8];
    const float* l1w = (const float*)d_in[9];
    const float* l1b = (const float*)d_in[10];
    const float* l2w = (const float*)d_in[11];
    const float* l2b = (const float*)d_in[12];
    float* out = (float*)d_out;

    const int n  = in_sizes[2];
    const int ne = in_sizes[1] / 2;
    const int* erow = ei;
    const int* ecol = ei + ne;

    // workspace carve
    char* w = (char*)d_ws;
    size_t off = 0;
    auto carve = [&](size_t bytes) {
        void* p = w + off;
        off += align256(bytes);
        return p;
    };
    int*   deg    = (int*)carve((size_t)n * 4);
    int*   rowptr = (int*)carve((size_t)(n + 1) * 4);
    int*   cursor = (int*)carve((size_t)n * 4);
    int*   bsum   = (int*)carve(1024 * 4);
    int*   ccol   = (int*)carve((size_t)ne * 4);
    float* cnorm  = (float*)carve((size_t)ne * 4);
    float* dinv   = (float*)carve((size_t)n * 4);
    float* coeff  = (float*)carve(3 * KORD * 4);
    float* sums   = (float*)carve((size_t)NGRAPHS * 64 * 4);
    float* cntf   = (float*)carve((size_t)NGRAPHS * 4);
    float* bufA   = (float*)carve((size_t)n * 64 * 4);
    float* bufB   = (float*)carve((size_t)n * 64 * 4);
    float* bufH   = (float*)carve((size_t)n * 64 * 4);
    (void)ws_size; (void)n_in; (void)out_size;

    const int nb256e = (ne + 255) / 256;
    const int nb256n = (n + 255) / 256;

    hipMemsetAsync(deg, 0, (size_t)n * 4, stream);
    hipMemsetAsync(sums, 0, (size_t)NGRAPHS * 64 * 4, stream);
    hipMemsetAsync(cntf, 0, (size_t)NGRAPHS * 4, stream);

    k_deg<<<nb256e, 256, 0, stream>>>(erow, deg, ne);
    k_dinv<<<nb256n, 256, 0, stream>>>(deg, dinv, n);
    k_scan1<<<nb256n, 256, 0, stream>>>(deg, rowptr, bsum, n);
    k_scan2<<<1, 1024, 0, stream>>>(bsum, nb256n);
    k_scan3<<<nb256n, 256, 0, stream>>>(rowptr, cursor, bsum, n, ne);
    k_fill<<<nb256e, 256, 0, stream>>>(erow, ecol, dinv, cursor, ccol, cnorm, ne);
    k_coeff<<<1, 64, 0, stream>>>(th1, ths, coeff);

    const int pb = (n + 3) / 4;  // 4 waves (rows) per 256-thread block
    float* H = bufH;

    for (int l = 0; l < 3; ++l) {
        const float* cf = coeff + l * KORD;
        const float* bias = (l == 0) ? b1 : bs + (l - 1) * HID;
        if (l == 0)
            k_gemm<FIN><<<pb, 256, 0, stream>>>(x, W1, bufA, n);
        else
            k_gemm<HID><<<pb, 256, 0, stream>>>(H, Ws + (size_t)(l - 1) * HID * HID, bufA, n);

        // t_prev = y (bufA); t_cur = prop(y) -> bufB; out = c0*tprev + c1*tcur
        k_prop<0><<<pb, 256, 0, stream>>>(rowptr, ccol, cnorm, bufA, bufB, bufA, H, cf, 0, bias, n);
        float* tp = bufA;
        float* tc = bufB;
        for (int k = 2; k < KORD; ++k) {
            if (k == KORD - 1)
                k_prop<2><<<pb, 256, 0, stream>>>(rowptr, ccol, cnorm, tc, tp, nullptr, H, cf, k, bias, n);
            else
                k_prop<1><<<pb, 256, 0, stream>>>(rowptr, ccol, cnorm, tc, tp, nullptr, H, cf, k, bias, n);
            float* t = tp; tp = tc; tc = t;
        }
    }

    const int poolwaves = (n + 31) / 32;
    const int poolblocks = (poolwaves * 64 + 255) / 256;
    k_pool<<<poolblocks, 256, 0, stream>>>(H, bat, sums, cntf, n);
    k_head<<<NGRAPHS, 64, 0, stream>>>(sums, cntf, l1w, l1b, l2w, l2b, out);
}

// Round 2
// 2802.251 us; speedup vs baseline: 2.2637x; 2.2637x over previous
//
#include <hip/hip_runtime.h>

#define NN 100000
#define NE 1600000
#define FIN 128
#define HID 64
#define HEADS 8
#define KORD 14
#define NGRAPHS 128
#define NCLASSES 10

static inline size_t align256(size_t x) { return (x + 255) & ~(size_t)255; }

// ---------------- setup kernels ----------------

__global__ void k_deg(const int* __restrict__ row, int* __restrict__ deg, int ne) {
    int e = blockIdx.x * 256 + threadIdx.x;
    if (e < ne) atomicAdd(&deg[row[e]], 1);
}

__global__ void k_dinv(const int* __restrict__ deg, float* __restrict__ dinv, int n) {
    int i = blockIdx.x * 256 + threadIdx.x;
    if (i < n) {
        float d = (float)deg[i];
        dinv[i] = rsqrtf(d < 1.f ? 1.f : d);
    }
}

// exclusive scan phase 1: per-block scan of 256 elements
__global__ void k_scan1(const int* __restrict__ deg, int* __restrict__ rowptr,
                        int* __restrict__ bsum, int n) {
    __shared__ int s[256];
    int t = threadIdx.x;
    int i = blockIdx.x * 256 + t;
    int v = (i < n) ? deg[i] : 0;
    s[t] = v;
    __syncthreads();
    for (int off = 1; off < 256; off <<= 1) {
        int add = (t >= off) ? s[t - off] : 0;
        __syncthreads();
        s[t] += add;
        __syncthreads();
    }
    if (i < n) rowptr[i] = s[t] - v;  // exclusive within block
    if (t == 255) bsum[blockIdx.x] = s[255];
}

// phase 2: single-block exclusive scan of block sums (nb <= 1024)
__global__ void k_scan2(int* __restrict__ bsum, int nb) {
    __shared__ int s[1024];
    int t = threadIdx.x;
    int v = (t < nb) ? bsum[t] : 0;
    s[t] = v;
    __syncthreads();
    for (int off = 1; off < 1024; off <<= 1) {
        int add = (t >= off) ? s[t - off] : 0;
        __syncthreads();
        s[t] += add;
        __syncthreads();
    }
    if (t < nb) bsum[t] = s[t] - v;  // exclusive
}

// phase 3: add block offsets; init cursor; write rowptr[n]
__global__ void k_scan3(int* __restrict__ rowptr, int* __restrict__ cursor,
                        const int* __restrict__ bsum, int n, int etot) {
    int i = blockIdx.x * 256 + threadIdx.x;
    if (i == 0) rowptr[n] = etot;
    if (i < n) {
        int v = rowptr[i] + bsum[i >> 8];
        rowptr[i] = v;
        cursor[i] = v;
    }
}

// fill packed CSR: ccw[pos] = {col, norm-weight-bits}
__global__ void k_fill(const int* __restrict__ row, const int* __restrict__ col,
                       const float* __restrict__ dinv, int* __restrict__ cursor,
                       int2* __restrict__ ccw, int ne) {
    int e = blockIdx.x * 256 + threadIdx.x;
    if (e >= ne) return;
    int r = row[e], c = col[e];
    int pos = atomicAdd(&cursor[r], 1);
    float w = dinv[r] * dinv[c];
    ccw[pos] = make_int2(c, __float_as_int(w));
}

// coeff[l][k] = mean over heads of theta[l][h][k]
__global__ void k_coeff(const float* __restrict__ th1, const float* __restrict__ ths,
                        float* __restrict__ coeff) {
    int i = threadIdx.x;
    if (i >= 3 * KORD) return;
    int l = i / KORD, k = i % KORD;
    const float* t = (l == 0) ? th1 : ths + (l - 1) * HEADS * KORD;
    float s = 0.f;
    for (int h = 0; h < HEADS; ++h) s += t[h * KORD + k];
    coeff[i] = s * (1.f / HEADS);
}

// ---------------- main compute kernels ----------------

// y[n x 64] = h[n x F] @ W[F x 64]
// block = 256 threads, tile = 64 rows x 64 cols, thread computes 4 rows x 4 cols.
template <int F>
__global__ __launch_bounds__(256) void k_gemm(const float* __restrict__ h,
                                              const float* __restrict__ W,
                                              float* __restrict__ y, int n) {
    __shared__ __align__(16) float Wl[F * 64];
    __shared__ float hl[64][F + 1];
    int tid = threadIdx.x;
    int row0 = blockIdx.x * 64;
    int nrows = n - row0;
    if (nrows > 64) nrows = 64;

    for (int i = tid; i < F * 64; i += 256) Wl[i] = W[i];
    for (int i = tid; i < nrows * F; i += 256) hl[i / F][i % F] = h[(size_t)row0 * F + i];
    __syncthreads();

    int rq = tid >> 4;        // 0..15 -> rows rq*4 .. rq*4+3
    int c0 = (tid & 15) * 4;  // col group
    float4 acc0 = {0, 0, 0, 0}, acc1 = {0, 0, 0, 0}, acc2 = {0, 0, 0, 0}, acc3 = {0, 0, 0, 0};
#pragma unroll 4
    for (int f = 0; f < F; ++f) {
        const float4 wv = *(const float4*)&Wl[f * 64 + c0];
        float h0 = hl[rq * 4 + 0][f];
        float h1 = hl[rq * 4 + 1][f];
        float h2 = hl[rq * 4 + 2][f];
        float h3 = hl[rq * 4 + 3][f];
        acc0.x = fmaf(h0, wv.x, acc0.x); acc0.y = fmaf(h0, wv.y, acc0.y);
        acc0.z = fmaf(h0, wv.z, acc0.z); acc0.w = fmaf(h0, wv.w, acc0.w);
        acc1.x = fmaf(h1, wv.x, acc1.x); acc1.y = fmaf(h1, wv.y, acc1.y);
        acc1.z = fmaf(h1, wv.z, acc1.z); acc1.w = fmaf(h1, wv.w, acc1.w);
        acc2.x = fmaf(h2, wv.x, acc2.x); acc2.y = fmaf(h2, wv.y, acc2.y);
        acc2.z = fmaf(h2, wv.z, acc2.z); acc2.w = fmaf(h2, wv.w, acc2.w);
        acc3.x = fmaf(h3, wv.x, acc3.x); acc3.y = fmaf(h3, wv.y, acc3.y);
        acc3.z = fmaf(h3, wv.z, acc3.z); acc3.w = fmaf(h3, wv.w, acc3.w);
    }
    float4* yp = (float4*)(y + (size_t)(row0 + rq * 4) * 64 + c0);
    int rem = nrows - rq * 4;
    if (rem > 0) {
        yp[0] = acc0;
        if (rem > 1) *(float4*)((char*)yp + 256) = acc1;
        if (rem > 2) *(float4*)((char*)yp + 512) = acc2;
        if (rem > 3) *(float4*)((char*)yp + 768) = acc3;
    }
}

// One wave per row, lane = feature. p = -sum_{e in row} w*src[col].
// Edge records for the row are loaded lane-parallel (coalesced), broadcast via shfl,
// and 8 gathers kept in flight per iteration.
// MODE 0: first step  : prevbuf = p ; out = c0*yA + c1*p
// MODE 1: middle step : tn = 2p - prev ; prev = tn ; out += c_k*tn
// MODE 2: last step   : tn = 2p - prev ; out = relu(out + c_k*tn + bias)
template <int MODE>
__global__ __launch_bounds__(256) void k_prop(const int* __restrict__ rowptr,
                                              const int2* __restrict__ ccw,
                                              const float* __restrict__ src,
                                              float* __restrict__ prevbuf,
                                              const float* __restrict__ yA,
                                              float* __restrict__ outbuf,
                                              const float* __restrict__ coeff, int k,
                                              const float* __restrict__ bias, int n) {
    int wid = (blockIdx.x * blockDim.x + threadIdx.x) >> 6;
    int lane = threadIdx.x & 63;
    if (wid >= n) return;
    int e0 = rowptr[wid], e1 = rowptr[wid + 1];
    float acc = 0.f;
    for (int base = e0; base < e1; base += 64) {
        int rem = e1 - base;
        int m = rem < 64 ? rem : 64;
        int cl = 0;
        float wl = 0.f;
        if (lane < m) {
            int2 rec = ccw[base + lane];
            cl = rec.x;
            wl = __int_as_float(rec.y);
        }
        for (int i = 0; i < m; i += 8) {
            int c0 = __shfl(cl, i + 0), c1 = __shfl(cl, i + 1);
            int c2 = __shfl(cl, i + 2), c3 = __shfl(cl, i + 3);
            int c4 = __shfl(cl, i + 4), c5 = __shfl(cl, i + 5);
            int c6 = __shfl(cl, i + 6), c7 = __shfl(cl, i + 7);
            float w0 = __shfl(wl, i + 0), w1 = __shfl(wl, i + 1);
            float w2 = __shfl(wl, i + 2), w3 = __shfl(wl, i + 3);
            float w4 = __shfl(wl, i + 4), w5 = __shfl(wl, i + 5);
            float w6 = __shfl(wl, i + 6), w7 = __shfl(wl, i + 7);
            float g0 = src[c0 * 64 + lane];
            float g1 = src[c1 * 64 + lane];
            float g2 = src[c2 * 64 + lane];
            float g3 = src[c3 * 64 + lane];
            float g4 = src[c4 * 64 + lane];
            float g5 = src[c5 * 64 + lane];
            float g6 = src[c6 * 64 + lane];
            float g7 = src[c7 * 64 + lane];
            acc = fmaf(w0, g0, acc);
            acc = fmaf(w1, g1, acc);
            acc = fmaf(w2, g2, acc);
            acc = fmaf(w3, g3, acc);
            acc = fmaf(w4, g4, acc);
            acc = fmaf(w5, g5, acc);
            acc = fmaf(w6, g6, acc);
            acc = fmaf(w7, g7, acc);
        }
    }
    float p = -acc;
    int idx = wid * 64 + lane;
    if (MODE == 0) {
        prevbuf[idx] = p;
        outbuf[idx] = coeff[0] * yA[idx] + coeff[1] * p;
    } else {
        float tn = 2.f * p - prevbuf[idx];
        if (MODE == 1) {
            prevbuf[idx] = tn;
            outbuf[idx] += coeff[k] * tn;
        } else {
            float v = outbuf[idx] + coeff[k] * tn + bias[lane];
            outbuf[idx] = v > 0.f ? v : 0.f;
        }
    }
}

// run-length compressed segment sum over sorted batch; wave = 32 nodes, lane = feature
__global__ void k_pool(const float* __restrict__ h, const int* __restrict__ batch,
                       float* __restrict__ sums, float* __restrict__ cntf, int n) {
    int wid = (blockIdx.x * blockDim.x + threadIdx.x) >> 6;
    int lane = threadIdx.x & 63;
    int start = wid * 32;
    if (start >= n) return;
    int end = start + 32;
    if (end > n) end = n;
    float acc = 0.f;
    int run = 0;
    int g = batch[start];
    for (int i = start; i < end; ++i) {
        int gi = batch[i];
        if (gi != g) {
            atomicAdd(&sums[g * 64 + lane], acc);
            if (lane == 0) atomicAdd(&cntf[g], (float)run);
            acc = 0.f;
            run = 0;
            g = gi;
        }
        acc += h[(size_t)i * 64 + lane];
        run++;
    }
    atomicAdd(&sums[g * 64 + lane], acc);
    if (lane == 0) atomicAdd(&cntf[g], (float)run);
}

// per-graph head: pooled = sums/cnt ; g = relu(pooled@w1+b1) ; logits = g@w2+b2 ; log_softmax
__global__ void k_head(const float* __restrict__ sums, const float* __restrict__ cntf,
                       const float* __restrict__ w1, const float* __restrict__ b1,
                       const float* __restrict__ w2, const float* __restrict__ b2,
                       float* __restrict__ out) {
    __shared__ float pl[64], gl[64], lg[NCLASSES];
    int g = blockIdx.x, t = threadIdx.x;
    float c = cntf[g];
    if (c < 1.f) c = 1.f;
    pl[t] = sums[g * 64 + t] / c;
    __syncthreads();
    float a = b1[t];
    for (int f = 0; f < 64; ++f) a += pl[f] * w1[f * 64 + t];
    gl[t] = a > 0.f ? a : 0.f;
    __syncthreads();
    if (t < NCLASSES) {
        float a2 = b2[t];
        for (int f = 0; f < 64; ++f) a2 += gl[f] * w2[f * NCLASSES + t];
        lg[t] = a2;
    }
    __syncthreads();
    if (t < NCLASSES) {
        float m = lg[0];
        for (int i = 1; i < NCLASSES; ++i) m = fmaxf(m, lg[i]);
        float s = 0.f;
        for (int i = 0; i < NCLASSES; ++i) s += expf(lg[i] - m);
        out[g * NCLASSES + t] = lg[t] - m - logf(s);
    }
}

// ---------------- host ----------------

extern "C" void kernel_launch(void* const* d_in, const int* in_sizes, int n_in,
                              void* d_out, int out_size, void* d_ws, size_t ws_size,
                              hipStream_t stream) {
    const float* x   = (const float*)d_in[0];
    const int*   ei  = (const int*)d_in[1];
    const int*   bat = (const int*)d_in[2];
    const float* W1  = (const float*)d_in[3];
    const float* th1 = (const float*)d_in[4];
    const float* b1  = (const float*)d_in[5];
    const float* Ws  = (const float*)d_in[6];
    const float* ths = (const float*)d_in[7];
    const float* bs  = (const float*)d_in[8];
    const float* l1w = (const float*)d_in[9];
    const float* l1b = (const float*)d_in[10];
    const float* l2w = (const float*)d_in[11];
    const float* l2b = (const float*)d_in[12];
    float* out = (float*)d_out;

    const int n  = in_sizes[2];
    const int ne = in_sizes[1] / 2;
    const int* erow = ei;
    const int* ecol = ei + ne;

    // workspace carve
    char* w = (char*)d_ws;
    size_t off = 0;
    auto carve = [&](size_t bytes) {
        void* p = w + off;
        off += align256(bytes);
        return p;
    };
    int*   deg    = (int*)carve((size_t)n * 4);
    int*   rowptr = (int*)carve((size_t)(n + 1) * 4);
    int*   cursor = (int*)carve((size_t)n * 4);
    int*   bsum   = (int*)carve(1024 * 4);
    int2*  ccw    = (int2*)carve((size_t)ne * 8);
    float* dinv   = (float*)carve((size_t)n * 4);
    float* coeff  = (float*)carve(3 * KORD * 4);
    float* sums   = (float*)carve((size_t)NGRAPHS * 64 * 4);
    float* cntf   = (float*)carve((size_t)NGRAPHS * 4);
    float* bufA   = (float*)carve((size_t)n * 64 * 4);
    float* bufB   = (float*)carve((size_t)n * 64 * 4);
    float* bufH   = (float*)carve((size_t)n * 64 * 4);
    (void)ws_size; (void)n_in; (void)out_size;

    const int nb256e = (ne + 255) / 256;
    const int nb256n = (n + 255) / 256;

    hipMemsetAsync(deg, 0, (size_t)n * 4, stream);
    hipMemsetAsync(sums, 0, (size_t)NGRAPHS * 64 * 4, stream);
    hipMemsetAsync(cntf, 0, (size_t)NGRAPHS * 4, stream);

    k_deg<<<nb256e, 256, 0, stream>>>(erow, deg, ne);
    k_dinv<<<nb256n, 256, 0, stream>>>(deg, dinv, n);
    k_scan1<<<nb256n, 256, 0, stream>>>(deg, rowptr, bsum, n);
    k_scan2<<<1, 1024, 0, stream>>>(bsum, nb256n);
    k_scan3<<<nb256n, 256, 0, stream>>>(rowptr, cursor, bsum, n, ne);
    k_fill<<<nb256e, 256, 0, stream>>>(erow, ecol, dinv, cursor, ccw, ne);
    k_coeff<<<1, 64, 0, stream>>>(th1, ths, coeff);

    const int pb = (n + 3) / 4;  // 4 waves (rows) per 256-thread block for k_prop
    float* H = bufH;

    for (int l = 0; l < 3; ++l) {
        const float* cf = coeff + l * KORD;
        const float* bias = (l == 0) ? b1 : bs + (l - 1) * HID;
        if (l == 0)
            k_gemm<FIN><<<(n + 63) / 64, 256, 0, stream>>>(x, W1, bufA, n);
        else
            k_gemm<HID><<<(n + 63) / 64, 256, 0, stream>>>(H, Ws + (size_t)(l - 1) * HID * HID, bufA, n);

        // t_prev = y (bufA); t_cur = prop(y) -> bufB; out = c0*tprev + c1*tcur
        k_prop<0><<<pb, 256, 0, stream>>>(rowptr, ccw, bufA, bufB, bufA, H, cf, 0, bias, n);
        float* tp = bufA;
        float* tc = bufB;
        for (int k = 2; k < KORD; ++k) {
            if (k == KORD - 1)
                k_prop<2><<<pb, 256, 0, stream>>>(rowptr, ccw, tc, tp, nullptr, H, cf, k, bias, n);
            else
                k_prop<1><<<pb, 256, 0, stream>>>(rowptr, ccw, tc, tp, nullptr, H, cf, k, bias, n);
            float* t = tp; tp = tc; tc = t;
        }
    }

    const int poolwaves = (n + 31) / 32;
    const int poolblocks = (poolwaves * 64 + 255) / 256;
    k_pool<<<poolblocks, 256, 0, stream>>>(H, bat, sums, cntf, n);
    k_head<<<NGRAPHS, 64, 0, stream>>>(sums, cntf, l1w, l1b, l2w, l2b, out);
}

// Round 3
// 2787.377 us; speedup vs baseline: 2.2758x; 1.0053x over previous
//
#include <hip/hip_runtime.h>

#define NN 100000
#define NE 1600000
#define FIN 128
#define HID 64
#define HEADS 8
#define KORD 14
#define NGRAPHS 128
#define NCLASSES 10

static inline size_t align256(size_t x) { return (x + 255) & ~(size_t)255; }

// ---------------- setup kernels ----------------

__global__ void k_deg(const int* __restrict__ row, int* __restrict__ deg, int ne) {
    int e = blockIdx.x * 256 + threadIdx.x;
    if (e < ne) atomicAdd(&deg[row[e]], 1);
}

__global__ void k_dinv(const int* __restrict__ deg, float* __restrict__ dinv, int n) {
    int i = blockIdx.x * 256 + threadIdx.x;
    if (i < n) {
        float d = (float)deg[i];
        dinv[i] = rsqrtf(d < 1.f ? 1.f : d);
    }
}

// exclusive scan phase 1: per-block scan of PADDED degrees ((deg+7)&~7)
__global__ void k_scan1(const int* __restrict__ deg, int* __restrict__ rowptr,
                        int* __restrict__ bsum, int n) {
    __shared__ int s[256];
    int t = threadIdx.x;
    int i = blockIdx.x * 256 + t;
    int v = (i < n) ? ((deg[i] + 7) & ~7) : 0;
    s[t] = v;
    __syncthreads();
    for (int off = 1; off < 256; off <<= 1) {
        int add = (t >= off) ? s[t - off] : 0;
        __syncthreads();
        s[t] += add;
        __syncthreads();
    }
    if (i < n) rowptr[i] = s[t] - v;  // exclusive within block
    if (t == 255) bsum[blockIdx.x] = s[255];
}

// phase 2: single-block exclusive scan of block sums (nb <= 1024)
__global__ void k_scan2(int* __restrict__ bsum, int nb) {
    __shared__ int s[1024];
    int t = threadIdx.x;
    int v = (t < nb) ? bsum[t] : 0;
    s[t] = v;
    __syncthreads();
    for (int off = 1; off < 1024; off <<= 1) {
        int add = (t >= off) ? s[t - off] : 0;
        __syncthreads();
        s[t] += add;
        __syncthreads();
    }
    if (t < nb) bsum[t] = s[t] - v;  // exclusive
}

// phase 3: add block offsets; init cursor; write rowptr[n] (total padded edges)
__global__ void k_scan3(int* __restrict__ rowptr, int* __restrict__ cursor,
                        const int* __restrict__ bsum, const int* __restrict__ deg, int n) {
    int i = blockIdx.x * 256 + threadIdx.x;
    if (i < n) {
        int v = rowptr[i] + bsum[i >> 8];
        rowptr[i] = v;
        cursor[i] = v;
        if (i == n - 1) rowptr[n] = v + ((deg[i] + 7) & ~7);
    }
}

// fill packed CSR: ccw[pos] = {col, norm-weight-bits}; pad slots stay {0, 0.0f} (memset)
__global__ void k_fill(const int* __restrict__ row, const int* __restrict__ col,
                       const float* __restrict__ dinv, int* __restrict__ cursor,
                       int2* __restrict__ ccw, int ne) {
    int e = blockIdx.x * 256 + threadIdx.x;
    if (e >= ne) return;
    int r = row[e], c = col[e];
    int pos = atomicAdd(&cursor[r], 1);
    float w = dinv[r] * dinv[c];
    ccw[pos] = make_int2(c, __float_as_int(w));
}

// coeff[l][k] = mean over heads of theta[l][h][k]
__global__ void k_coeff(const float* __restrict__ th1, const float* __restrict__ ths,
                        float* __restrict__ coeff) {
    int i = threadIdx.x;
    if (i >= 3 * KORD) return;
    int l = i / KORD, k = i % KORD;
    const float* t = (l == 0) ? th1 : ths + (l - 1) * HEADS * KORD;
    float s = 0.f;
    for (int h = 0; h < HEADS; ++h) s += t[h * KORD + k];
    coeff[i] = s * (1.f / HEADS);
}

// ---------------- main compute kernels ----------------

// y[n x 64] = h[n x F] @ W[F x 64]
// block = 256 threads, tile = 64 rows x 64 cols, thread computes 4 rows x 4 cols.
template <int F>
__global__ __launch_bounds__(256) void k_gemm(const float* __restrict__ h,
                                              const float* __restrict__ W,
                                              float* __restrict__ y, int n) {
    __shared__ __align__(16) float Wl[F * 64];
    __shared__ float hl[64][F + 1];
    int tid = threadIdx.x;
    int row0 = blockIdx.x * 64;
    int nrows = n - row0;
    if (nrows > 64) nrows = 64;

    for (int i = tid; i < F * 64; i += 256) Wl[i] = W[i];
    for (int i = tid; i < nrows * F; i += 256) hl[i / F][i % F] = h[(size_t)row0 * F + i];
    __syncthreads();

    int rq = tid >> 4;        // 0..15 -> rows rq*4 .. rq*4+3
    int c0 = (tid & 15) * 4;  // col group
    float4 acc0 = {0, 0, 0, 0}, acc1 = {0, 0, 0, 0}, acc2 = {0, 0, 0, 0}, acc3 = {0, 0, 0, 0};
#pragma unroll 4
    for (int f = 0; f < F; ++f) {
        const float4 wv = *(const float4*)&Wl[f * 64 + c0];
        float h0 = hl[rq * 4 + 0][f];
        float h1 = hl[rq * 4 + 1][f];
        float h2 = hl[rq * 4 + 2][f];
        float h3 = hl[rq * 4 + 3][f];
        acc0.x = fmaf(h0, wv.x, acc0.x); acc0.y = fmaf(h0, wv.y, acc0.y);
        acc0.z = fmaf(h0, wv.z, acc0.z); acc0.w = fmaf(h0, wv.w, acc0.w);
        acc1.x = fmaf(h1, wv.x, acc1.x); acc1.y = fmaf(h1, wv.y, acc1.y);
        acc1.z = fmaf(h1, wv.z, acc1.z); acc1.w = fmaf(h1, wv.w, acc1.w);
        acc2.x = fmaf(h2, wv.x, acc2.x); acc2.y = fmaf(h2, wv.y, acc2.y);
        acc2.z = fmaf(h2, wv.z, acc2.z); acc2.w = fmaf(h2, wv.w, acc2.w);
        acc3.x = fmaf(h3, wv.x, acc3.x); acc3.y = fmaf(h3, wv.y, acc3.y);
        acc3.z = fmaf(h3, wv.z, acc3.z); acc3.w = fmaf(h3, wv.w, acc3.w);
    }
    float4* yp = (float4*)(y + (size_t)(row0 + rq * 4) * 64 + c0);
    int rem = nrows - rq * 4;
    if (rem > 0) {
        yp[0] = acc0;
        if (rem > 1) *(float4*)((char*)yp + 256) = acc1;
        if (rem > 2) *(float4*)((char*)yp + 512) = acc2;
        if (rem > 3) *(float4*)((char*)yp + 768) = acc3;
    }
}

// One wave per row, lane = feature. p = -sum_{e in row} w*src[col].
// Edge records are wave-uniform -> loaded via SGPR (s_load) thanks to readfirstlane;
// rows are padded to a multiple of 8 records ({0,0.0f} pads are no-op fmas), so the
// inner loop is a single uniform 8-edge block with 8 independent gathers in flight.
// MODE 0: first step  : prevbuf = p ; out = c0*yA + c1*p
// MODE 1: middle step : tn = 2p - prev ; prev = tn ; out += c_k*tn
// MODE 2: last step   : tn = 2p - prev ; out = relu(out + c_k*tn + bias)
template <int MODE>
__global__ __launch_bounds__(256) void k_prop(const int* __restrict__ rowptr,
                                              const int2* __restrict__ ccw,
                                              const float* __restrict__ src,
                                              float* __restrict__ prevbuf,
                                              const float* __restrict__ yA,
                                              float* __restrict__ outbuf,
                                              const float* __restrict__ coeff, int k,
                                              const float* __restrict__ bias, int n) {
    int wid = (blockIdx.x * blockDim.x + threadIdx.x) >> 6;
    int lane = threadIdx.x & 63;
    if (wid >= n) return;
    wid = __builtin_amdgcn_readfirstlane(wid);
    const int e0 = __builtin_amdgcn_readfirstlane(rowptr[wid]);
    const int e1 = __builtin_amdgcn_readfirstlane(rowptr[wid + 1]);
    float acc0 = 0.f, acc1 = 0.f;
    for (int e = e0; e < e1; e += 8) {
        const int4* q = (const int4*)(ccw + e);
        int4 r0 = q[0];
        int4 r1 = q[1];
        int4 r2 = q[2];
        int4 r3 = q[3];
        float g0 = src[r0.x * 64 + lane];
        float g1 = src[r0.z * 64 + lane];
        float g2 = src[r1.x * 64 + lane];
        float g3 = src[r1.z * 64 + lane];
        float g4 = src[r2.x * 64 + lane];
        float g5 = src[r2.z * 64 + lane];
        float g6 = src[r3.x * 64 + lane];
        float g7 = src[r3.z * 64 + lane];
        acc0 = fmaf(__int_as_float(r0.y), g0, acc0);
        acc1 = fmaf(__int_as_float(r0.w), g1, acc1);
        acc0 = fmaf(__int_as_float(r1.y), g2, acc0);
        acc1 = fmaf(__int_as_float(r1.w), g3, acc1);
        acc0 = fmaf(__int_as_float(r2.y), g4, acc0);
        acc1 = fmaf(__int_as_float(r2.w), g5, acc1);
        acc0 = fmaf(__int_as_float(r3.y), g6, acc0);
        acc1 = fmaf(__int_as_float(r3.w), g7, acc1);
    }
    float p = -(acc0 + acc1);
    int idx = wid * 64 + lane;
    if (MODE == 0) {
        prevbuf[idx] = p;
        outbuf[idx] = coeff[0] * yA[idx] + coeff[1] * p;
    } else {
        float tn = 2.f * p - prevbuf[idx];
        if (MODE == 1) {
            prevbuf[idx] = tn;
            outbuf[idx] += coeff[k] * tn;
        } else {
            float v = outbuf[idx] + coeff[k] * tn + bias[lane];
            outbuf[idx] = v > 0.f ? v : 0.f;
        }
    }
}

// run-length compressed segment sum over sorted batch; wave = 32 nodes, lane = feature
__global__ void k_pool(const float* __restrict__ h, const int* __restrict__ batch,
                       float* __restrict__ sums, float* __restrict__ cntf, int n) {
    int wid = (blockIdx.x * blockDim.x + threadIdx.x) >> 6;
    int lane = threadIdx.x & 63;
    int start = wid * 32;
    if (start >= n) return;
    int end = start + 32;
    if (end > n) end = n;
    float acc = 0.f;
    int run = 0;
    int g = batch[start];
    for (int i = start; i < end; ++i) {
        int gi = batch[i];
        if (gi != g) {
            atomicAdd(&sums[g * 64 + lane], acc);
            if (lane == 0) atomicAdd(&cntf[g], (float)run);
            acc = 0.f;
            run = 0;
            g = gi;
        }
        acc += h[(size_t)i * 64 + lane];
        run++;
    }
    atomicAdd(&sums[g * 64 + lane], acc);
    if (lane == 0) atomicAdd(&cntf[g], (float)run);
}

// per-graph head: pooled = sums/cnt ; g = relu(pooled@w1+b1) ; logits = g@w2+b2 ; log_softmax
__global__ void k_head(const float* __restrict__ sums, const float* __restrict__ cntf,
                       const float* __restrict__ w1, const float* __restrict__ b1,
                       const float* __restrict__ w2, const float* __restrict__ b2,
                       float* __restrict__ out) {
    __shared__ float pl[64], gl[64], lg[NCLASSES];
    int g = blockIdx.x, t = threadIdx.x;
    float c = cntf[g];
    if (c < 1.f) c = 1.f;
    pl[t] = sums[g * 64 + t] / c;
    __syncthreads();
    float a = b1[t];
    for (int f = 0; f < 64; ++f) a += pl[f] * w1[f * 64 + t];
    gl[t] = a > 0.f ? a : 0.f;
    __syncthreads();
    if (t < NCLASSES) {
        float a2 = b2[t];
        for (int f = 0; f < 64; ++f) a2 += gl[f] * w2[f * NCLASSES + t];
        lg[t] = a2;
    }
    __syncthreads();
    if (t < NCLASSES) {
        float m = lg[0];
        for (int i = 1; i < NCLASSES; ++i) m = fmaxf(m, lg[i]);
        float s = 0.f;
        for (int i = 0; i < NCLASSES; ++i) s += expf(lg[i] - m);
        out[g * NCLASSES + t] = lg[t] - m - logf(s);
    }
}

// ---------------- host ----------------

extern "C" void kernel_launch(void* const* d_in, const int* in_sizes, int n_in,
                              void* d_out, int out_size, void* d_ws, size_t ws_size,
                              hipStream_t stream) {
    const float* x   = (const float*)d_in[0];
    const int*   ei  = (const int*)d_in[1];
    const int*   bat = (const int*)d_in[2];
    const float* W1  = (const float*)d_in[3];
    const float* th1 = (const float*)d_in[4];
    const float* b1  = (const float*)d_in[5];
    const float* Ws  = (const float*)d_in[6];
    const float* ths = (const float*)d_in[7];
    const float* bs  = (const float*)d_in[8];
    const float* l1w = (const float*)d_in[9];
    const float* l1b = (const float*)d_in[10];
    const float* l2w = (const float*)d_in[11];
    const float* l2b = (const float*)d_in[12];
    float* out = (float*)d_out;

    const int n  = in_sizes[2];
    const int ne = in_sizes[1] / 2;
    const int* erow = ei;
    const int* ecol = ei + ne;

    // workspace carve
    char* w = (char*)d_ws;
    size_t off = 0;
    auto carve = [&](size_t bytes) {
        void* p = w + off;
        off += align256(bytes);
        return p;
    };
    const size_t ne_pad = (size_t)ne + 7 * (size_t)n + 8;  // max padded records
    int*   deg    = (int*)carve((size_t)n * 4);
    int*   rowptr = (int*)carve((size_t)(n + 1) * 4);
    int*   cursor = (int*)carve((size_t)n * 4);
    int*   bsum   = (int*)carve(1024 * 4);
    int2*  ccw    = (int2*)carve(ne_pad * 8);
    float* dinv   = (float*)carve((size_t)n * 4);
    float* coeff  = (float*)carve(3 * KORD * 4);
    float* sums   = (float*)carve((size_t)NGRAPHS * 64 * 4);
    float* cntf   = (float*)carve((size_t)NGRAPHS * 4);
    float* bufA   = (float*)carve((size_t)n * 64 * 4);
    float* bufB   = (float*)carve((size_t)n * 64 * 4);
    float* bufH   = (float*)carve((size_t)n * 64 * 4);
    (void)ws_size; (void)n_in; (void)out_size;

    const int nb256e = (ne + 255) / 256;
    const int nb256n = (n + 255) / 256;

    hipMemsetAsync(deg, 0, (size_t)n * 4, stream);
    hipMemsetAsync(ccw, 0, ne_pad * 8, stream);  // pad records -> {c=0, w=0.0f}
    hipMemsetAsync(sums, 0, (size_t)NGRAPHS * 64 * 4, stream);
    hipMemsetAsync(cntf, 0, (size_t)NGRAPHS * 4, stream);

    k_deg<<<nb256e, 256, 0, stream>>>(erow, deg, ne);
    k_dinv<<<nb256n, 256, 0, stream>>>(deg, dinv, n);
    k_scan1<<<nb256n, 256, 0, stream>>>(deg, rowptr, bsum, n);
    k_scan2<<<1, 1024, 0, stream>>>(bsum, nb256n);
    k_scan3<<<nb256n, 256, 0, stream>>>(rowptr, cursor, bsum, deg, n);
    k_fill<<<nb256e, 256, 0, stream>>>(erow, ecol, dinv, cursor, ccw, ne);
    k_coeff<<<1, 64, 0, stream>>>(th1, ths, coeff);

    const int pb = (n + 3) / 4;  // 4 waves (rows) per 256-thread block for k_prop
    float* H = bufH;

    for (int l = 0; l < 3; ++l) {
        const float* cf = coeff + l * KORD;
        const float* bias = (l == 0) ? b1 : bs + (l - 1) * HID;
        if (l == 0)
            k_gemm<FIN><<<(n + 63) / 64, 256, 0, stream>>>(x, W1, bufA, n);
        else
            k_gemm<HID><<<(n + 63) / 64, 256, 0, stream>>>(H, Ws + (size_t)(l - 1) * HID * HID, bufA, n);

        // t_prev = y (bufA); t_cur = prop(y) -> bufB; out = c0*tprev + c1*tcur
        k_prop<0><<<pb, 256, 0, stream>>>(rowptr, ccw, bufA, bufB, bufA, H, cf, 0, bias, n);
        float* tp = bufA;
        float* tc = bufB;
        for (int k = 2; k < KORD; ++k) {
            if (k == KORD - 1)
                k_prop<2><<<pb, 256, 0, stream>>>(rowptr, ccw, tc, tp, nullptr, H, cf, k, bias, n);
            else
                k_prop<1><<<pb, 256, 0, stream>>>(rowptr, ccw, tc, tp, nullptr, H, cf, k, bias, n);
            float* t = tp; tp = tc; tc = t;
        }
    }

    const int poolwaves = (n + 31) / 32;
    const int poolblocks = (poolwaves * 64 + 255) / 256;
    k_pool<<<poolblocks, 256, 0, stream>>>(H, bat, sums, cntf, n);
    k_head<<<NGRAPHS, 64, 0, stream>>>(sums, cntf, l1w, l1b, l2w, l2b, out);
}

// Round 4
// 2101.020 us; speedup vs baseline: 3.0193x; 1.3267x over previous
//
#include <hip/hip_runtime.h>

#define NN 100000
#define NE 1600000
#define FIN 128
#define HID 64
#define HEADS 8
#define KORD 14
#define NGRAPHS 128
#define NCLASSES 10

static inline size_t align256(size_t x) { return (x + 255) & ~(size_t)255; }

// round-to-nearest-even f32 -> bf16 (as uint16 in low bits)
__device__ __forceinline__ unsigned bfr(float x) {
    unsigned u = __float_as_uint(x);
    return (u + 0x7fffu + ((u >> 16) & 1u)) >> 16;
}
__device__ __forceinline__ unsigned bfpack(float lo, float hi) {
    return bfr(lo) | (bfr(hi) << 16);
}

// ---------------- setup kernels ----------------

__global__ void k_deg(const int* __restrict__ row, int* __restrict__ deg, int ne) {
    int e = blockIdx.x * 256 + threadIdx.x;
    if (e < ne) atomicAdd(&deg[row[e]], 1);
}

__global__ void k_dinv(const int* __restrict__ deg, float* __restrict__ dinv, int n) {
    int i = blockIdx.x * 256 + threadIdx.x;
    if (i < n) {
        float d = (float)deg[i];
        dinv[i] = rsqrtf(d < 1.f ? 1.f : d);
    }
}

// exclusive scan phase 1: per-block scan of PADDED degrees ((deg+7)&~7)
__global__ void k_scan1(const int* __restrict__ deg, int* __restrict__ rowptr,
                        int* __restrict__ bsum, int n) {
    __shared__ int s[256];
    int t = threadIdx.x;
    int i = blockIdx.x * 256 + t;
    int v = (i < n) ? ((deg[i] + 7) & ~7) : 0;
    s[t] = v;
    __syncthreads();
    for (int off = 1; off < 256; off <<= 1) {
        int add = (t >= off) ? s[t - off] : 0;
        __syncthreads();
        s[t] += add;
        __syncthreads();
    }
    if (i < n) rowptr[i] = s[t] - v;  // exclusive within block
    if (t == 255) bsum[blockIdx.x] = s[255];
}

// phase 2: single-block exclusive scan of block sums (nb <= 1024)
__global__ void k_scan2(int* __restrict__ bsum, int nb) {
    __shared__ int s[1024];
    int t = threadIdx.x;
    int v = (t < nb) ? bsum[t] : 0;
    s[t] = v;
    __syncthreads();
    for (int off = 1; off < 1024; off <<= 1) {
        int add = (t >= off) ? s[t - off] : 0;
        __syncthreads();
        s[t] += add;
        __syncthreads();
    }
    if (t < nb) bsum[t] = s[t] - v;  // exclusive
}

// phase 3: add block offsets; init cursor; write rowptr[n] (total padded edges)
__global__ void k_scan3(int* __restrict__ rowptr, int* __restrict__ cursor,
                        const int* __restrict__ bsum, const int* __restrict__ deg, int n) {
    int i = blockIdx.x * 256 + threadIdx.x;
    if (i < n) {
        int v = rowptr[i] + bsum[i >> 8];
        rowptr[i] = v;
        cursor[i] = v;
        if (i == n - 1) rowptr[n] = v + ((deg[i] + 7) & ~7);
    }
}

// fill packed CSR: ccw[pos] = {col, norm-weight-bits}; pad slots stay {0, 0.0f} (memset)
__global__ void k_fill(const int* __restrict__ row, const int* __restrict__ col,
                       const float* __restrict__ dinv, int* __restrict__ cursor,
                       int2* __restrict__ ccw, int ne) {
    int e = blockIdx.x * 256 + threadIdx.x;
    if (e >= ne) return;
    int r = row[e], c = col[e];
    int pos = atomicAdd(&cursor[r], 1);
    float w = dinv[r] * dinv[c];
    ccw[pos] = make_int2(c, __float_as_int(w));
}

// coeff[l][k] = mean over heads of theta[l][h][k]
__global__ void k_coeff(const float* __restrict__ th1, const float* __restrict__ ths,
                        float* __restrict__ coeff) {
    int i = threadIdx.x;
    if (i >= 3 * KORD) return;
    int l = i / KORD, k = i % KORD;
    const float* t = (l == 0) ? th1 : ths + (l - 1) * HEADS * KORD;
    float s = 0.f;
    for (int h = 0; h < HEADS; ++h) s += t[h * KORD + k];
    coeff[i] = s * (1.f / HEADS);
}

// ---------------- main compute kernels ----------------

// y[n x 64] = h[n x F] @ W[F x 64], plus bf16 copy ybf.
// block = 256 threads, tile = 64 rows x 64 cols, thread computes 4 rows x 4 cols.
template <int F>
__global__ __launch_bounds__(256) void k_gemm(const float* __restrict__ h,
                                              const float* __restrict__ W,
                                              float* __restrict__ y,
                                              unsigned short* __restrict__ ybf, int n) {
    __shared__ __align__(16) float Wl[F * 64];
    __shared__ float hl[64][F + 1];
    int tid = threadIdx.x;
    int row0 = blockIdx.x * 64;
    int nrows = n - row0;
    if (nrows > 64) nrows = 64;

    for (int i = tid; i < F * 64; i += 256) Wl[i] = W[i];
    for (int i = tid; i < nrows * F; i += 256) hl[i / F][i % F] = h[(size_t)row0 * F + i];
    __syncthreads();

    int rq = tid >> 4;        // 0..15 -> rows rq*4 .. rq*4+3
    int c0 = (tid & 15) * 4;  // col group
    float4 acc0 = {0, 0, 0, 0}, acc1 = {0, 0, 0, 0}, acc2 = {0, 0, 0, 0}, acc3 = {0, 0, 0, 0};
#pragma unroll 4
    for (int f = 0; f < F; ++f) {
        const float4 wv = *(const float4*)&Wl[f * 64 + c0];
        float h0 = hl[rq * 4 + 0][f];
        float h1 = hl[rq * 4 + 1][f];
        float h2 = hl[rq * 4 + 2][f];
        float h3 = hl[rq * 4 + 3][f];
        acc0.x = fmaf(h0, wv.x, acc0.x); acc0.y = fmaf(h0, wv.y, acc0.y);
        acc0.z = fmaf(h0, wv.z, acc0.z); acc0.w = fmaf(h0, wv.w, acc0.w);
        acc1.x = fmaf(h1, wv.x, acc1.x); acc1.y = fmaf(h1, wv.y, acc1.y);
        acc1.z = fmaf(h1, wv.z, acc1.z); acc1.w = fmaf(h1, wv.w, acc1.w);
        acc2.x = fmaf(h2, wv.x, acc2.x); acc2.y = fmaf(h2, wv.y, acc2.y);
        acc2.z = fmaf(h2, wv.z, acc2.z); acc2.w = fmaf(h2, wv.w, acc2.w);
        acc3.x = fmaf(h3, wv.x, acc3.x); acc3.y = fmaf(h3, wv.y, acc3.y);
        acc3.z = fmaf(h3, wv.z, acc3.z); acc3.w = fmaf(h3, wv.w, acc3.w);
    }
    int rem = nrows - rq * 4;
    float4 accs[4] = {acc0, acc1, acc2, acc3};
#pragma unroll
    for (int r = 0; r < 4; ++r) {
        if (r < rem) {
            size_t base = (size_t)(row0 + rq * 4 + r) * 64 + c0;
            *(float4*)(y + base) = accs[r];
            uint2 p;
            p.x = bfpack(accs[r].x, accs[r].y);
            p.y = bfpack(accs[r].z, accs[r].w);
            *(uint2*)(ybf + base) = p;
        }
    }
}

// One wave per row; 2 edges processed per step (low half lanes: edge A, high half: edge B).
// Gather source is bf16 [n][64]; each lane loads 1 dword = 2 features.
// p = -sum_{e in row} w*src[col]. Rows padded to multiple of 8 records ({0,0.0f} no-ops).
// MODE 0: first step  : prevbuf = p (f32) ; nextbf = bf16(p) ; out = c0*yA + c1*p
// MODE 1: middle step : tn = 2p - prev ; prevbuf = tn ; nextbf = bf16(tn) ; out += c_k*tn
// MODE 2: last step   : tn = 2p - prev ; out = relu(out + c_k*tn + bias)
template <int MODE>
__global__ __launch_bounds__(256) void k_prop(const int* __restrict__ rowptr,
                                              const int2* __restrict__ ccw,
                                              const unsigned short* __restrict__ srcbf,
                                              float* __restrict__ prevbuf,
                                              unsigned short* __restrict__ nextbf,
                                              const float* __restrict__ yA,
                                              float* __restrict__ outbuf,
                                              const float* __restrict__ coeff, int k,
                                              const float* __restrict__ bias, int n) {
    int wid = (blockIdx.x * blockDim.x + threadIdx.x) >> 6;
    int lane = threadIdx.x & 63;
    if (wid >= n) return;
    wid = __builtin_amdgcn_readfirstlane(wid);
    const int e0 = __builtin_amdgcn_readfirstlane(rowptr[wid]);
    const int e1 = __builtin_amdgcn_readfirstlane(rowptr[wid + 1]);
    const bool hi = lane >= 32;
    const int fl = lane & 31;  // feature-pair index: features 2*fl, 2*fl+1
    float acc0 = 0.f, acc1 = 0.f;
    for (int e = e0; e < e1; e += 8) {
        const int4* q = (const int4*)(ccw + e);
        int4 r0 = q[0];
        int4 r1 = q[1];
        int4 r2 = q[2];
        int4 r3 = q[3];
        int cA = hi ? r0.z : r0.x;
        int cB = hi ? r1.z : r1.x;
        int cC = hi ? r2.z : r2.x;
        int cD = hi ? r3.z : r3.x;
        float wA = __int_as_float(hi ? r0.w : r0.y);
        float wB = __int_as_float(hi ? r1.w : r1.y);
        float wC = __int_as_float(hi ? r2.w : r2.y);
        float wD = __int_as_float(hi ? r3.w : r3.y);
        unsigned uA = ((const unsigned*)(srcbf + ((size_t)cA << 6)))[fl];
        unsigned uB = ((const unsigned*)(srcbf + ((size_t)cB << 6)))[fl];
        unsigned uC = ((const unsigned*)(srcbf + ((size_t)cC << 6)))[fl];
        unsigned uD = ((const unsigned*)(srcbf + ((size_t)cD << 6)))[fl];
        acc0 = fmaf(wA, __uint_as_float(uA << 16), acc0);
        acc1 = fmaf(wA, __uint_as_float(uA & 0xffff0000u), acc1);
        acc0 = fmaf(wB, __uint_as_float(uB << 16), acc0);
        acc1 = fmaf(wB, __uint_as_float(uB & 0xffff0000u), acc1);
        acc0 = fmaf(wC, __uint_as_float(uC << 16), acc0);
        acc1 = fmaf(wC, __uint_as_float(uC & 0xffff0000u), acc1);
        acc0 = fmaf(wD, __uint_as_float(uD << 16), acc0);
        acc1 = fmaf(wD, __uint_as_float(uD & 0xffff0000u), acc1);
    }
    // combine the two halves (edge-set A partials + edge-set B partials)
    acc0 += __shfl_xor(acc0, 32, 64);
    acc1 += __shfl_xor(acc1, 32, 64);
    if (hi) return;
    float px = -acc0;  // feature 2*fl
    float py = -acc1;  // feature 2*fl+1
    size_t base = (size_t)wid * 64 + fl * 2;
    if (MODE == 0) {
        *(float2*)(prevbuf + base) = make_float2(px, py);
        *(unsigned*)(nextbf + base) = bfpack(px, py);
        float2 yv = *(const float2*)(yA + base);
        float c0v = coeff[0], c1v = coeff[1];
        *(float2*)(outbuf + base) = make_float2(c0v * yv.x + c1v * px, c0v * yv.y + c1v * py);
    } else {
        float2 pv = *(const float2*)(prevbuf + base);
        float tnx = 2.f * px - pv.x;
        float tny = 2.f * py - pv.y;
        float ck = coeff[k];
        float2 ov = *(const float2*)(outbuf + base);
        if (MODE == 1) {
            *(float2*)(prevbuf + base) = make_float2(tnx, tny);
            *(unsigned*)(nextbf + base) = bfpack(tnx, tny);
            *(float2*)(outbuf + base) = make_float2(ov.x + ck * tnx, ov.y + ck * tny);
        } else {
            float2 bv = *(const float2*)(bias + fl * 2);
            float vx = ov.x + ck * tnx + bv.x;
            float vy = ov.y + ck * tny + bv.y;
            *(float2*)(outbuf + base) = make_float2(vx > 0.f ? vx : 0.f, vy > 0.f ? vy : 0.f);
        }
    }
}

// run-length compressed segment sum over sorted batch; wave = 32 nodes, lane = feature
__global__ void k_pool(const float* __restrict__ h, const int* __restrict__ batch,
                       float* __restrict__ sums, float* __restrict__ cntf, int n) {
    int wid = (blockIdx.x * blockDim.x + threadIdx.x) >> 6;
    int lane = threadIdx.x & 63;
    int start = wid * 32;
    if (start >= n) return;
    int end = start + 32;
    if (end > n) end = n;
    float acc = 0.f;
    int run = 0;
    int g = batch[start];
    for (int i = start; i < end; ++i) {
        int gi = batch[i];
        if (gi != g) {
            atomicAdd(&sums[g * 64 + lane], acc);
            if (lane == 0) atomicAdd(&cntf[g], (float)run);
            acc = 0.f;
            run = 0;
            g = gi;
        }
        acc += h[(size_t)i * 64 + lane];
        run++;
    }
    atomicAdd(&sums[g * 64 + lane], acc);
    if (lane == 0) atomicAdd(&cntf[g], (float)run);
}

// per-graph head: pooled = sums/cnt ; g = relu(pooled@w1+b1) ; logits = g@w2+b2 ; log_softmax
__global__ void k_head(const float* __restrict__ sums, const float* __restrict__ cntf,
                       const float* __restrict__ w1, const float* __restrict__ b1,
                       const float* __restrict__ w2, const float* __restrict__ b2,
                       float* __restrict__ out) {
    __shared__ float pl[64], gl[64], lg[NCLASSES];
    int g = blockIdx.x, t = threadIdx.x;
    float c = cntf[g];
    if (c < 1.f) c = 1.f;
    pl[t] = sums[g * 64 + t] / c;
    __syncthreads();
    float a = b1[t];
    for (int f = 0; f < 64; ++f) a += pl[f] * w1[f * 64 + t];
    gl[t] = a > 0.f ? a : 0.f;
    __syncthreads();
    if (t < NCLASSES) {
        float a2 = b2[t];
        for (int f = 0; f < 64; ++f) a2 += gl[f] * w2[f * NCLASSES + t];
        lg[t] = a2;
    }
    __syncthreads();
    if (t < NCLASSES) {
        float m = lg[0];
        for (int i = 1; i < NCLASSES; ++i) m = fmaxf(m, lg[i]);
        float s = 0.f;
        for (int i = 0; i < NCLASSES; ++i) s += expf(lg[i] - m);
        out[g * NCLASSES + t] = lg[t] - m - logf(s);
    }
}

// ---------------- host ----------------

extern "C" void kernel_launch(void* const* d_in, const int* in_sizes, int n_in,
                              void* d_out, int out_size, void* d_ws, size_t ws_size,
                              hipStream_t stream) {
    const float* x   = (const float*)d_in[0];
    const int*   ei  = (const int*)d_in[1];
    const int*   bat = (const int*)d_in[2];
    const float* W1  = (const float*)d_in[3];
    const float* th1 = (const float*)d_in[4];
    const float* b1  = (const float*)d_in[5];
    const float* Ws  = (const float*)d_in[6];
    const float* ths = (const float*)d_in[7];
    const float* bs  = (const float*)d_in[8];
    const float* l1w = (const float*)d_in[9];
    const float* l1b = (const float*)d_in[10];
    const float* l2w = (const float*)d_in[11];
    const float* l2b = (const float*)d_in[12];
    float* out = (float*)d_out;

    const int n  = in_sizes[2];
    const int ne = in_sizes[1] / 2;
    const int* erow = ei;
    const int* ecol = ei + ne;

    // workspace carve
    char* w = (char*)d_ws;
    size_t off = 0;
    auto carve = [&](size_t bytes) {
        void* p = w + off;
        off += align256(bytes);
        return p;
    };
    const size_t ne_pad = (size_t)ne + 7 * (size_t)n + 8;  // max padded records
    int*   deg    = (int*)carve((size_t)n * 4);
    int*   rowptr = (int*)carve((size_t)(n + 1) * 4);
    int*   cursor = (int*)carve((size_t)n * 4);
    int*   bsum   = (int*)carve(1024 * 4);
    int2*  ccw    = (int2*)carve(ne_pad * 8);
    float* dinv   = (float*)carve((size_t)n * 4);
    float* coeff  = (float*)carve(3 * KORD * 4);
    float* sums   = (float*)carve((size_t)NGRAPHS * 64 * 4);
    float* cntf   = (float*)carve((size_t)NGRAPHS * 4);
    float* bufA   = (float*)carve((size_t)n * 64 * 4);
    float* bufB   = (float*)carve((size_t)n * 64 * 4);
    float* bufH   = (float*)carve((size_t)n * 64 * 4);
    unsigned short* bfA = (unsigned short*)carve((size_t)n * 64 * 2);
    unsigned short* bfB = (unsigned short*)carve((size_t)n * 64 * 2);
    (void)ws_size; (void)n_in; (void)out_size;

    const int nb256e = (ne + 255) / 256;
    const int nb256n = (n + 255) / 256;

    hipMemsetAsync(deg, 0, (size_t)n * 4, stream);
    hipMemsetAsync(ccw, 0, ne_pad * 8, stream);  // pad records -> {c=0, w=0.0f}
    hipMemsetAsync(sums, 0, (size_t)NGRAPHS * 64 * 4, stream);
    hipMemsetAsync(cntf, 0, (size_t)NGRAPHS * 4, stream);

    k_deg<<<nb256e, 256, 0, stream>>>(erow, deg, ne);
    k_dinv<<<nb256n, 256, 0, stream>>>(deg, dinv, n);
    k_scan1<<<nb256n, 256, 0, stream>>>(deg, rowptr, bsum, n);
    k_scan2<<<1, 1024, 0, stream>>>(bsum, nb256n);
    k_scan3<<<nb256n, 256, 0, stream>>>(rowptr, cursor, bsum, deg, n);
    k_fill<<<nb256e, 256, 0, stream>>>(erow, ecol, dinv, cursor, ccw, ne);
    k_coeff<<<1, 64, 0, stream>>>(th1, ths, coeff);

    const int pb = (n + 3) / 4;  // 4 waves (rows) per 256-thread block for k_prop
    float* H = bufH;

    for (int l = 0; l < 3; ++l) {
        const float* cf = coeff + l * KORD;
        const float* bias = (l == 0) ? b1 : bs + (l - 1) * HID;
        if (l == 0)
            k_gemm<FIN><<<(n + 63) / 64, 256, 0, stream>>>(x, W1, bufA, bfA, n);
        else
            k_gemm<HID><<<(n + 63) / 64, 256, 0, stream>>>(H, Ws + (size_t)(l - 1) * HID * HID, bufA, bfA, n);

        // t_prev = y (bufA f32); t_cur = prop(y) -> bufB f32 + bfB bf16
        k_prop<0><<<pb, 256, 0, stream>>>(rowptr, ccw, bfA, bufB, bfB, bufA, H, cf, 0, bias, n);
        float* tp = bufA;
        float* tc = bufB;
        unsigned short* bfp = bfA;
        unsigned short* bfc = bfB;
        for (int k = 2; k < KORD; ++k) {
            if (k == KORD - 1)
                k_prop<2><<<pb, 256, 0, stream>>>(rowptr, ccw, bfc, tp, nullptr, nullptr, H, cf, k, bias, n);
            else
                k_prop<1><<<pb, 256, 0, stream>>>(rowptr, ccw, bfc, tp, bfp, nullptr, H, cf, k, bias, n);
            float* t = tp; tp = tc; tc = t;
            unsigned short* tb = bfp; bfp = bfc; bfc = tb;
        }
    }

    const int poolwaves = (n + 31) / 32;
    const int poolblocks = (poolwaves * 64 + 255) / 256;
    k_pool<<<poolblocks, 256, 0, stream>>>(H, bat, sums, cntf, n);
    k_head<<<NGRAPHS, 64, 0, stream>>>(sums, cntf, l1w, l1b, l2w, l2b, out);
}

// Round 5
// 1973.646 us; speedup vs baseline: 3.2141x; 1.0645x over previous
//
#include <hip/hip_runtime.h>

#define NN 100000
#define NE 1600000
#define FIN 128
#define HID 64
#define HEADS 8
#define KORD 14
#define NGRAPHS 128
#define NCLASSES 10

static inline size_t align256(size_t x) { return (x + 255) & ~(size_t)255; }

// round-to-nearest-even f32 -> bf16 (as uint16 in low bits)
__device__ __forceinline__ unsigned bfr(float x) {
    unsigned u = __float_as_uint(x);
    return (u + 0x7fffu + ((u >> 16) & 1u)) >> 16;
}
__device__ __forceinline__ unsigned bfpack(float lo, float hi) {
    return bfr(lo) | (bfr(hi) << 16);
}
__device__ __forceinline__ float bflo(unsigned u) { return __uint_as_float(u << 16); }
__device__ __forceinline__ float bfhi(unsigned u) { return __uint_as_float(u & 0xffff0000u); }

// ---------------- setup kernels ----------------

__global__ void k_deg(const int* __restrict__ row, int* __restrict__ deg, int ne) {
    int e = blockIdx.x * 256 + threadIdx.x;
    if (e < ne) atomicAdd(&deg[row[e]], 1);
}

__global__ void k_dinv(const int* __restrict__ deg, float* __restrict__ dinv, int n) {
    int i = blockIdx.x * 256 + threadIdx.x;
    if (i < n) {
        float d = (float)deg[i];
        dinv[i] = rsqrtf(d < 1.f ? 1.f : d);
    }
}

// exclusive scan phase 1: per-block scan of PADDED degrees ((deg+7)&~7)
__global__ void k_scan1(const int* __restrict__ deg, int* __restrict__ rowptr,
                        int* __restrict__ bsum, int n) {
    __shared__ int s[256];
    int t = threadIdx.x;
    int i = blockIdx.x * 256 + t;
    int v = (i < n) ? ((deg[i] + 7) & ~7) : 0;
    s[t] = v;
    __syncthreads();
    for (int off = 1; off < 256; off <<= 1) {
        int add = (t >= off) ? s[t - off] : 0;
        __syncthreads();
        s[t] += add;
        __syncthreads();
    }
    if (i < n) rowptr[i] = s[t] - v;  // exclusive within block
    if (t == 255) bsum[blockIdx.x] = s[255];
}

// phase 2: single-block exclusive scan of block sums (nb <= 1024)
__global__ void k_scan2(int* __restrict__ bsum, int nb) {
    __shared__ int s[1024];
    int t = threadIdx.x;
    int v = (t < nb) ? bsum[t] : 0;
    s[t] = v;
    __syncthreads();
    for (int off = 1; off < 1024; off <<= 1) {
        int add = (t >= off) ? s[t - off] : 0;
        __syncthreads();
        s[t] += add;
        __syncthreads();
    }
    if (t < nb) bsum[t] = s[t] - v;  // exclusive
}

// phase 3: add block offsets; init cursor; write rowptr[n] (total padded edges)
__global__ void k_scan3(int* __restrict__ rowptr, int* __restrict__ cursor,
                        const int* __restrict__ bsum, const int* __restrict__ deg, int n) {
    int i = blockIdx.x * 256 + threadIdx.x;
    if (i < n) {
        int v = rowptr[i] + bsum[i >> 8];
        rowptr[i] = v;
        cursor[i] = v;
        if (i == n - 1) rowptr[n] = v + ((deg[i] + 7) & ~7);
    }
}

// fill packed CSR: ccw[pos] = {col, norm-weight-bits}; pad slots stay {0, 0.0f} (memset)
__global__ void k_fill(const int* __restrict__ row, const int* __restrict__ col,
                       const float* __restrict__ dinv, int* __restrict__ cursor,
                       int2* __restrict__ ccw, int ne) {
    int e = blockIdx.x * 256 + threadIdx.x;
    if (e >= ne) return;
    int r = row[e], c = col[e];
    int pos = atomicAdd(&cursor[r], 1);
    float w = dinv[r] * dinv[c];
    ccw[pos] = make_int2(c, __float_as_int(w));
}

// coeff[l][k] = mean over heads of theta[l][h][k]
__global__ void k_coeff(const float* __restrict__ th1, const float* __restrict__ ths,
                        float* __restrict__ coeff) {
    int i = threadIdx.x;
    if (i >= 3 * KORD) return;
    int l = i / KORD, k = i % KORD;
    const float* t = (l == 0) ? th1 : ths + (l - 1) * HEADS * KORD;
    float s = 0.f;
    for (int h = 0; h < HEADS; ++h) s += t[h * KORD + k];
    coeff[i] = s * (1.f / HEADS);
}

// ---------------- main compute kernels ----------------

// slab0[n x 64] (bf16) = h[n x F] @ W[F x 64]
// block = 256 threads, tile = 64 rows x 64 cols, thread computes 4 rows x 4 cols.
template <int F>
__global__ __launch_bounds__(256) void k_gemm(const float* __restrict__ h,
                                              const float* __restrict__ W,
                                              unsigned short* __restrict__ ybf, int n) {
    __shared__ __align__(16) float Wl[F * 64];
    __shared__ float hl[64][F + 1];
    int tid = threadIdx.x;
    int row0 = blockIdx.x * 64;
    int nrows = n - row0;
    if (nrows > 64) nrows = 64;

    for (int i = tid; i < F * 64; i += 256) Wl[i] = W[i];
    for (int i = tid; i < nrows * F; i += 256) hl[i / F][i % F] = h[(size_t)row0 * F + i];
    __syncthreads();

    int rq = tid >> 4;        // 0..15 -> rows rq*4 .. rq*4+3
    int c0 = (tid & 15) * 4;  // col group
    float4 acc0 = {0, 0, 0, 0}, acc1 = {0, 0, 0, 0}, acc2 = {0, 0, 0, 0}, acc3 = {0, 0, 0, 0};
#pragma unroll 4
    for (int f = 0; f < F; ++f) {
        const float4 wv = *(const float4*)&Wl[f * 64 + c0];
        float h0 = hl[rq * 4 + 0][f];
        float h1 = hl[rq * 4 + 1][f];
        float h2 = hl[rq * 4 + 2][f];
        float h3 = hl[rq * 4 + 3][f];
        acc0.x = fmaf(h0, wv.x, acc0.x); acc0.y = fmaf(h0, wv.y, acc0.y);
        acc0.z = fmaf(h0, wv.z, acc0.z); acc0.w = fmaf(h0, wv.w, acc0.w);
        acc1.x = fmaf(h1, wv.x, acc1.x); acc1.y = fmaf(h1, wv.y, acc1.y);
        acc1.z = fmaf(h1, wv.z, acc1.z); acc1.w = fmaf(h1, wv.w, acc1.w);
        acc2.x = fmaf(h2, wv.x, acc2.x); acc2.y = fmaf(h2, wv.y, acc2.y);
        acc2.z = fmaf(h2, wv.z, acc2.z); acc2.w = fmaf(h2, wv.w, acc2.w);
        acc3.x = fmaf(h3, wv.x, acc3.x); acc3.y = fmaf(h3, wv.y, acc3.y);
        acc3.z = fmaf(h3, wv.z, acc3.z); acc3.w = fmaf(h3, wv.w, acc3.w);
    }
    int rem = nrows - rq * 4;
    float4 accs[4] = {acc0, acc1, acc2, acc3};
#pragma unroll
    for (int r = 0; r < 4; ++r) {
        if (r < rem) {
            size_t base = (size_t)(row0 + rq * 4 + r) * 64 + c0;
            uint2 p;
            p.x = bfpack(accs[r].x, accs[r].y);
            p.y = bfpack(accs[r].z, accs[r].w);
            *(uint2*)(ybf + base) = p;
        }
    }
}

// One wave per row; 2 edges per step (low half lanes: edge A, high half: edge B).
// Gather source is bf16 [n][64]; each lane loads 1 dword = 2 features.
// p = -sum_{e in row} w*src[col]. Rows padded to multiple of 8 records ({0,0.0f} no-ops).
// FIRST: dst = bf16(p)               (T1 = L~ y)
// else : dst = bf16(2p - prev_bf16)  (T_k = 2 L~ T_{k-1} - T_{k-2})
template <bool FIRST>
__global__ __launch_bounds__(256) void k_prop(const int* __restrict__ rowptr,
                                              const int2* __restrict__ ccw,
                                              const unsigned short* __restrict__ srcbf,
                                              const unsigned short* __restrict__ prevbf,
                                              unsigned short* __restrict__ dstbf, int n) {
    int wid = (blockIdx.x * blockDim.x + threadIdx.x) >> 6;
    int lane = threadIdx.x & 63;
    if (wid >= n) return;
    wid = __builtin_amdgcn_readfirstlane(wid);
    const int e0 = __builtin_amdgcn_readfirstlane(rowptr[wid]);
    const int e1 = __builtin_amdgcn_readfirstlane(rowptr[wid + 1]);
    const bool hi = lane >= 32;
    const int fl = lane & 31;  // feature-pair index: features 2*fl, 2*fl+1
    float acc0 = 0.f, acc1 = 0.f;
    for (int e = e0; e < e1; e += 8) {
        const int4* q = (const int4*)(ccw + e);
        int4 r0 = q[0];
        int4 r1 = q[1];
        int4 r2 = q[2];
        int4 r3 = q[3];
        int cA = hi ? r0.z : r0.x;
        int cB = hi ? r1.z : r1.x;
        int cC = hi ? r2.z : r2.x;
        int cD = hi ? r3.z : r3.x;
        float wA = __int_as_float(hi ? r0.w : r0.y);
        float wB = __int_as_float(hi ? r1.w : r1.y);
        float wC = __int_as_float(hi ? r2.w : r2.y);
        float wD = __int_as_float(hi ? r3.w : r3.y);
        unsigned uA = ((const unsigned*)(srcbf + ((size_t)cA << 6)))[fl];
        unsigned uB = ((const unsigned*)(srcbf + ((size_t)cB << 6)))[fl];
        unsigned uC = ((const unsigned*)(srcbf + ((size_t)cC << 6)))[fl];
        unsigned uD = ((const unsigned*)(srcbf + ((size_t)cD << 6)))[fl];
        acc0 = fmaf(wA, bflo(uA), acc0);
        acc1 = fmaf(wA, bfhi(uA), acc1);
        acc0 = fmaf(wB, bflo(uB), acc0);
        acc1 = fmaf(wB, bfhi(uB), acc1);
        acc0 = fmaf(wC, bflo(uC), acc0);
        acc1 = fmaf(wC, bfhi(uC), acc1);
        acc0 = fmaf(wD, bflo(uD), acc0);
        acc1 = fmaf(wD, bfhi(uD), acc1);
    }
    // combine the two halves (edge-set A partials + edge-set B partials)
    acc0 += __shfl_xor(acc0, 32, 64);
    acc1 += __shfl_xor(acc1, 32, 64);
    if (hi) return;
    float px = -acc0;  // feature 2*fl
    float py = -acc1;  // feature 2*fl+1
    int di = wid * 32 + fl;  // dword index in [n][32] dword view
    if (!FIRST) {
        unsigned pu = ((const unsigned*)prevbf)[di];
        px = 2.f * px - bflo(pu);
        py = 2.f * py - bfhi(pu);
    }
    ((unsigned*)dstbf)[di] = bfpack(px, py);
}

// accumulate 7 Chebyshev terms: out(+)= sum_j cf[j]*S_j ; FINAL adds bias+relu in place.
template <bool FINAL>
__global__ __launch_bounds__(256) void k_acc(const unsigned short* __restrict__ s0,
                                             const unsigned short* __restrict__ s1,
                                             const unsigned short* __restrict__ s2,
                                             const unsigned short* __restrict__ s3,
                                             const unsigned short* __restrict__ s4,
                                             const unsigned short* __restrict__ s5,
                                             const unsigned short* __restrict__ s6,
                                             const float* __restrict__ cf,
                                             const float* __restrict__ bias,
                                             float* __restrict__ outacc, int n32) {
    int i = blockIdx.x * 256 + threadIdx.x;
    if (i >= n32) return;
    float c0 = cf[0], c1 = cf[1], c2 = cf[2], c3 = cf[3], c4 = cf[4], c5 = cf[5], c6 = cf[6];
    unsigned u;
    float ax, ay;
    u = ((const unsigned*)s0)[i]; ax = c0 * bflo(u); ay = c0 * bfhi(u);
    u = ((const unsigned*)s1)[i]; ax = fmaf(c1, bflo(u), ax); ay = fmaf(c1, bfhi(u), ay);
    u = ((const unsigned*)s2)[i]; ax = fmaf(c2, bflo(u), ax); ay = fmaf(c2, bfhi(u), ay);
    u = ((const unsigned*)s3)[i]; ax = fmaf(c3, bflo(u), ax); ay = fmaf(c3, bfhi(u), ay);
    u = ((const unsigned*)s4)[i]; ax = fmaf(c4, bflo(u), ax); ay = fmaf(c4, bfhi(u), ay);
    u = ((const unsigned*)s5)[i]; ax = fmaf(c5, bflo(u), ax); ay = fmaf(c5, bfhi(u), ay);
    u = ((const unsigned*)s6)[i]; ax = fmaf(c6, bflo(u), ax); ay = fmaf(c6, bfhi(u), ay);
    float2* op = (float2*)outacc + i;
    float2 prev = *op;
    if (FINAL) {
        int fp = (i & 31) * 2;
        float vx = prev.x + ax + bias[fp];
        float vy = prev.y + ay + bias[fp + 1];
        *op = make_float2(vx > 0.f ? vx : 0.f, vy > 0.f ? vy : 0.f);
    } else {
        *op = make_float2(ax, ay);
    }
}

// run-length compressed segment sum over sorted batch; wave = 32 nodes, lane = feature
__global__ void k_pool(const float* __restrict__ h, const int* __restrict__ batch,
                       float* __restrict__ sums, float* __restrict__ cntf, int n) {
    int wid = (blockIdx.x * blockDim.x + threadIdx.x) >> 6;
    int lane = threadIdx.x & 63;
    int start = wid * 32;
    if (start >= n) return;
    int end = start + 32;
    if (end > n) end = n;
    float acc = 0.f;
    int run = 0;
    int g = batch[start];
    for (int i = start; i < end; ++i) {
        int gi = batch[i];
        if (gi != g) {
            atomicAdd(&sums[g * 64 + lane], acc);
            if (lane == 0) atomicAdd(&cntf[g], (float)run);
            acc = 0.f;
            run = 0;
            g = gi;
        }
        acc += h[(size_t)i * 64 + lane];
        run++;
    }
    atomicAdd(&sums[g * 64 + lane], acc);
    if (lane == 0) atomicAdd(&cntf[g], (float)run);
}

// per-graph head: pooled = sums/cnt ; g = relu(pooled@w1+b1) ; logits = g@w2+b2 ; log_softmax
__global__ void k_head(const float* __restrict__ sums, const float* __restrict__ cntf,
                       const float* __restrict__ w1, const float* __restrict__ b1,
                       const float* __restrict__ w2, const float* __restrict__ b2,
                       float* __restrict__ out) {
    __shared__ float pl[64], gl[64], lg[NCLASSES];
    int g = blockIdx.x, t = threadIdx.x;
    float c = cntf[g];
    if (c < 1.f) c = 1.f;
    pl[t] = sums[g * 64 + t] / c;
    __syncthreads();
    float a = b1[t];
    for (int f = 0; f < 64; ++f) a += pl[f] * w1[f * 64 + t];
    gl[t] = a > 0.f ? a : 0.f;
    __syncthreads();
    if (t < NCLASSES) {
        float a2 = b2[t];
        for (int f = 0; f < 64; ++f) a2 += gl[f] * w2[f * NCLASSES + t];
        lg[t] = a2;
    }
    __syncthreads();
    if (t < NCLASSES) {
        float m = lg[0];
        for (int i = 1; i < NCLASSES; ++i) m = fmaxf(m, lg[i]);
        float s = 0.f;
        for (int i = 0; i < NCLASSES; ++i) s += expf(lg[i] - m);
        out[g * NCLASSES + t] = lg[t] - m - logf(s);
    }
}

// ---------------- host ----------------

extern "C" void kernel_launch(void* const* d_in, const int* in_sizes, int n_in,
                              void* d_out, int out_size, void* d_ws, size_t ws_size,
                              hipStream_t stream) {
    const float* x   = (const float*)d_in[0];
    const int*   ei  = (const int*)d_in[1];
    const int*   bat = (const int*)d_in[2];
    const float* W1  = (const float*)d_in[3];
    const float* th1 = (const float*)d_in[4];
    const float* b1  = (const float*)d_in[5];
    const float* Ws  = (const float*)d_in[6];
    const float* ths = (const float*)d_in[7];
    const float* bs  = (const float*)d_in[8];
    const float* l1w = (const float*)d_in[9];
    const float* l1b = (const float*)d_in[10];
    const float* l2w = (const float*)d_in[11];
    const float* l2b = (const float*)d_in[12];
    float* out = (float*)d_out;

    const int n  = in_sizes[2];
    const int ne = in_sizes[1] / 2;
    const int* erow = ei;
    const int* ecol = ei + ne;

    // workspace carve
    char* w = (char*)d_ws;
    size_t off = 0;
    auto carve = [&](size_t bytes) {
        void* p = w + off;
        off += align256(bytes);
        return p;
    };
    const size_t ne_pad = (size_t)ne + 7 * (size_t)n + 8;  // max padded records
    int*   deg    = (int*)carve((size_t)n * 4);
    int*   rowptr = (int*)carve((size_t)(n + 1) * 4);
    int*   cursor = (int*)carve((size_t)n * 4);
    int*   bsum   = (int*)carve(1024 * 4);
    int2*  ccw    = (int2*)carve(ne_pad * 8);
    float* dinv   = (float*)carve((size_t)n * 4);
    float* coeff  = (float*)carve(3 * KORD * 4);
    float* sums   = (float*)carve((size_t)NGRAPHS * 64 * 4);
    float* cntf   = (float*)carve((size_t)NGRAPHS * 4);
    float* outacc = (float*)carve((size_t)n * 64 * 4);  // doubles as H after FINAL acc
    unsigned short* slab[7];
    for (int s = 0; s < 7; ++s) slab[s] = (unsigned short*)carve((size_t)n * 64 * 2);
    (void)ws_size; (void)n_in; (void)out_size;

    const int nb256e = (ne + 255) / 256;
    const int nb256n = (n + 255) / 256;

    hipMemsetAsync(deg, 0, (size_t)n * 4, stream);
    hipMemsetAsync(ccw, 0, ne_pad * 8, stream);  // pad records -> {c=0, w=0.0f}
    hipMemsetAsync(sums, 0, (size_t)NGRAPHS * 64 * 4, stream);
    hipMemsetAsync(cntf, 0, (size_t)NGRAPHS * 4, stream);

    k_deg<<<nb256e, 256, 0, stream>>>(erow, deg, ne);
    k_dinv<<<nb256n, 256, 0, stream>>>(deg, dinv, n);
    k_scan1<<<nb256n, 256, 0, stream>>>(deg, rowptr, bsum, n);
    k_scan2<<<1, 1024, 0, stream>>>(bsum, nb256n);
    k_scan3<<<nb256n, 256, 0, stream>>>(rowptr, cursor, bsum, deg, n);
    k_fill<<<nb256e, 256, 0, stream>>>(erow, ecol, dinv, cursor, ccw, ne);
    k_coeff<<<1, 64, 0, stream>>>(th1, ths, coeff);

    const int pb = (n + 3) / 4;       // 4 waves (rows) per 256-thread block for k_prop
    const int n32 = n * 32;           // dword pairs per feature map
    const int ab = (n32 + 255) / 256; // blocks for k_acc

    for (int l = 0; l < 3; ++l) {
        const float* cf = coeff + l * KORD;
        const float* bias = (l == 0) ? b1 : bs + (l - 1) * HID;

        // T0 = h @ W  (bf16 slab0)
        if (l == 0)
            k_gemm<FIN><<<(n + 63) / 64, 256, 0, stream>>>(x, W1, slab[0], n);
        else
            k_gemm<HID><<<(n + 63) / 64, 256, 0, stream>>>(outacc, Ws + (size_t)(l - 1) * HID * HID, slab[0], n);

        // T1 = L~ T0
        k_prop<true><<<pb, 256, 0, stream>>>(rowptr, ccw, slab[0], nullptr, slab[1], n);
        // T2..T6
        for (int k = 2; k <= 6; ++k)
            k_prop<false><<<pb, 256, 0, stream>>>(rowptr, ccw, slab[k - 1], slab[k - 2], slab[k], n);
        // out = sum_{k=0..6} c_k T_k
        k_acc<false><<<ab, 256, 0, stream>>>(slab[0], slab[1], slab[2], slab[3], slab[4],
                                             slab[5], slab[6], cf, nullptr, outacc, n32);
        // T7..T13 (slab[k%7]); slab j holds T_{7+j}
        for (int k = 7; k <= 13; ++k)
            k_prop<false><<<pb, 256, 0, stream>>>(rowptr, ccw, slab[(k - 1) % 7], slab[(k - 2) % 7],
                                                  slab[k % 7], n);
        // H = relu(out + sum_{k=7..13} c_k T_k + bias)  (in place into outacc)
        k_acc<true><<<ab, 256, 0, stream>>>(slab[0], slab[1], slab[2], slab[3], slab[4],
                                            slab[5], slab[6], cf + 7, bias, outacc, n32);
    }

    const int poolwaves = (n + 31) / 32;
    const int poolblocks = (poolwaves * 64 + 255) / 256;
    k_pool<<<poolblocks, 256, 0, stream>>>(outacc, bat, sums, cntf, n);
    k_head<<<NGRAPHS, 64, 0, stream>>>(sums, cntf, l1w, l1b, l2w, l2b, out);
}